// Round 9
// baseline (454.854 us; speedup 1.0000x reference)
//
#include <hip/hip_runtime.h>
#include <math.h>

#define DE 768
#define DP 320
#define HID 768
#define LL 512
#define BB 64
#define M_TOT (BB * LL)     // 32768 rows
#define HD (HID * DE)       // 589824

typedef _Float16 half8 __attribute__((ext_vector_type(8)));
typedef _Float16 half4 __attribute__((ext_vector_type(4)));
typedef _Float16 half2v __attribute__((ext_vector_type(2)));
typedef float floatx4 __attribute__((ext_vector_type(4)));

// async global->LDS, 16B per lane; LDS dest = wave-uniform base + lane*16
__device__ __forceinline__ void gload16(const void* g, void* l) {
    __builtin_amdgcn_global_load_lds(
        (const __attribute__((address_space(1))) unsigned int*)g,
        (__attribute__((address_space(3))) unsigned int*)l, 16, 0, 0);
}

// ---- fast transcendentals ----
__device__ __forceinline__ float fast_sigmoid(float x) {
    return __builtin_amdgcn_rcpf(1.f + __expf(-x));
}
__device__ __forceinline__ float fast_tanh(float x) {
    return 2.f * __builtin_amdgcn_rcpf(1.f + __expf(-2.f * x)) - 1.f;
}

// ---- monotone float <-> uint key (max via unsigned atomicMax) ----
__device__ __forceinline__ unsigned fkey(float v) {
    unsigned u = __float_as_uint(v);
    return (u & 0x80000000u) ? ~u : (u | 0x80000000u);
}
__device__ __forceinline__ float funkey(unsigned k) {
    unsigned u = (k & 0x80000000u) ? (k & 0x7FFFFFFFu) : ~k;
    return __uint_as_float(u);
}

// ---- prep: fp32->fp16 converts + Wc transpose, grid-stride (no block churn) ----
__global__ __launch_bounds__(256) void prep_all(
    const float* __restrict__ Xe, const float* __restrict__ W1,
    const float* __restrict__ W2, const float* __restrict__ Wc,
    _Float16* __restrict__ Xe_h, _Float16* __restrict__ W1_h,
    _Float16* __restrict__ W2_h, _Float16* __restrict__ WcT)
{
    const int t0 = blockIdx.x * 256 + threadIdx.x;
    const int stride = gridDim.x * 256;
    for (int i = t0; i < 6291456; i += stride) {          // Xe: 25.2M elems
        float4 v = ((const float4*)Xe)[i];
        half4 h = {(_Float16)v.x, (_Float16)v.y, (_Float16)v.z, (_Float16)v.w};
        *(half4*)&Xe_h[(size_t)i * 4] = h;
    }
    for (int i = t0; i < 147456; i += stride) {           // W1
        float4 v = ((const float4*)W1)[i];
        half4 h = {(_Float16)v.x, (_Float16)v.y, (_Float16)v.z, (_Float16)v.w};
        *(half4*)&W1_h[(size_t)i * 4] = h;
    }
    for (int i = t0; i < 61440; i += stride) {            // W2
        float4 v = ((const float4*)W2)[i];
        half4 h = {(_Float16)v.x, (_Float16)v.y, (_Float16)v.z, (_Float16)v.w};
        *(half4*)&W2_h[(size_t)i * 4] = h;
    }
    for (int i = t0; i < 589824; i += stride) {           // Wc transpose
        float a = Wc[(size_t)i * 3 + 0];
        float b = Wc[(size_t)i * 3 + 1];
        float c = Wc[(size_t)i * 3 + 2];
        WcT[i]          = (_Float16)a;
        WcT[HD + i]     = (_Float16)b;
        WcT[2 * HD + i] = (_Float16)c;
    }
}

// ---- K1: X = sigmoid(Xe*W1^T+b1)*Xe + (1-sig)*tanh(Xp*W2^T+b2) ----
// fp16 Xe staging + XCD-aware tile swizzle (unchanged from R8).
__global__ __launch_bounds__(256) void gate_kernel(
    const _Float16* __restrict__ Xe_h, const float* __restrict__ Xp,
    const _Float16* __restrict__ W1_h, const float* __restrict__ b1,
    const _Float16* __restrict__ W2_h, const float* __restrict__ b2,
    _Float16* __restrict__ Xout)
{
    __shared__ __align__(16) char smem[24576];
    _Float16 (*As)[32] = (_Float16 (*)[32])smem;            // phase B A fp16, 8 KB
    float    (*Af)[32] = (float (*)[32])smem;               // phase A A fp32, 16 KB
    _Float16 (*Bs)[32] = (_Float16 (*)[32])(smem + 16384);  // B fp16, 8 KB
    unsigned (*Ep)[132] = (unsigned (*)[132])smem;          // epilogue (g,t)

    const int tid = threadIdx.x;
    const int lane = tid & 63, wid = tid >> 6;
    const int quad = lane >> 4, l15 = lane & 15;
    const int wm = (wid & 1) * 64, wn = (wid >> 1) * 64;
    const int linear = blockIdx.y * 6 + blockIdx.x;   // 0..1535
    const int xcd = linear & 7, kk = linear >> 3;     // kk 0..191
    const int n0 = (kk % 6) * 128;
    const int m0 = (xcd * 32 + kk / 6) * 128;
    const int i4 = lane >> 2, c8 = (lane & 3) * 8;
    const int c8x = c8 ^ ((i4 & 3) * 8);
    const int i8 = lane >> 3, c4 = (lane & 7) * 4;
    const int c4x = c4 ^ ((i8 & 3) * 8);
    const int rsw = (l15 & 3) * 8;

    floatx4 acc[4][4] = {};

    // ---- phase A: Xp fp32 (K=320) x W2_h^T ----
    for (int k0 = 0; k0 < DP; k0 += 32) {
        __syncthreads();
        #pragma unroll
        for (int t = 0; t < 4; ++t) {
            int rb = wid * 32 + t * 8;
            gload16(&Xp[(size_t)(m0 + rb + i8) * DP + k0 + c4x], &Af[rb][0]);
        }
        #pragma unroll
        for (int t = 0; t < 2; ++t) {
            int rb = wid * 32 + t * 16;
            gload16(&W2_h[(size_t)(n0 + rb + i4) * DP + k0 + c8x], &Bs[rb][0]);
        }
        __syncthreads();
        half8 af[4], bf[4];
        #pragma unroll
        for (int i = 0; i < 4; ++i) {
            int row = wm + i * 16 + l15;
            int sb = (quad * 8) ^ rsw;
            float4 x0 = *(float4*)&Af[row][sb];
            float4 x1 = *(float4*)&Af[row][sb + 4];
            half8 h = {(_Float16)x0.x, (_Float16)x0.y, (_Float16)x0.z, (_Float16)x0.w,
                       (_Float16)x1.x, (_Float16)x1.y, (_Float16)x1.z, (_Float16)x1.w};
            af[i] = h;
        }
        #pragma unroll
        for (int j = 0; j < 4; ++j)
            bf[j] = *(half8*)&Bs[wn + j * 16 + l15][(quad * 8) ^ rsw];
        #pragma unroll
        for (int i = 0; i < 4; ++i)
            #pragma unroll
            for (int j = 0; j < 4; ++j)
                acc[i][j] = __builtin_amdgcn_mfma_f32_16x16x32_f16(af[i], bf[j], acc[i][j], 0, 0, 0);
    }

    // collapse acc -> t = tanh(acc + b2) packed fp16; reuse acc for phase B
    half4 tpk[4][4];
    #pragma unroll
    for (int j = 0; j < 4; ++j) {
        float b2v = b2[n0 + wn + j * 16 + l15];
        #pragma unroll
        for (int i = 0; i < 4; ++i) {
            half4 h;
            #pragma unroll
            for (int r = 0; r < 4; ++r)
                h[r] = (_Float16)fast_tanh(acc[i][j][r] + b2v);
            tpk[i][j] = h;
            acc[i][j] = (floatx4){0.f, 0.f, 0.f, 0.f};
        }
    }

    // ---- phase B: Xe_h fp16 (K=768) x W1_h^T ----
    for (int k0 = 0; k0 < DE; k0 += 32) {
        __syncthreads();
        #pragma unroll
        for (int t = 0; t < 2; ++t) {
            int rb = wid * 32 + t * 16;
            gload16(&Xe_h[(size_t)(m0 + rb + i4) * DE + k0 + c8x], &As[rb][0]);
            gload16(&W1_h[(size_t)(n0 + rb + i4) * DE + k0 + c8x], &Bs[rb][0]);
        }
        __syncthreads();
        half8 af[4], bf[4];
        #pragma unroll
        for (int i = 0; i < 4; ++i)
            af[i] = *(half8*)&As[wm + i * 16 + l15][(quad * 8) ^ rsw];
        #pragma unroll
        for (int j = 0; j < 4; ++j)
            bf[j] = *(half8*)&Bs[wn + j * 16 + l15][(quad * 8) ^ rsw];
        #pragma unroll
        for (int i = 0; i < 4; ++i)
            #pragma unroll
            for (int j = 0; j < 4; ++j)
                acc[i][j] = __builtin_amdgcn_mfma_f32_16x16x32_f16(af[i], bf[j], acc[i][j], 0, 0, 0);
    }

    // ---- epilogue via LDS: coalesced global IO ----
    float b1v[4];
    #pragma unroll
    for (int j = 0; j < 4; ++j) b1v[j] = b1[n0 + wn + j * 16 + l15];

    #pragma unroll
    for (int p = 0; p < 4; ++p) {
        __syncthreads();
        if ((wm >> 6) == (p >> 1)) {
            #pragma unroll
            for (int ii = 0; ii < 2; ++ii) {
                int i = (p & 1) * 2 + ii;
                #pragma unroll
                for (int j = 0; j < 4; ++j) {
                    int col = wn + j * 16 + l15;
                    #pragma unroll
                    for (int r = 0; r < 4; ++r) {
                        int row_l = ii * 16 + quad * 4 + r;
                        float g = fast_sigmoid(acc[i][j][r] + b1v[j]);
                        half2v gt;
                        gt[0] = (_Float16)g;
                        gt[1] = tpk[i][j][r];
                        Ep[row_l][col] = __builtin_bit_cast(unsigned, gt);
                    }
                }
            }
        }
        __syncthreads();
        #pragma unroll
        for (int q = 0; q < 4; ++q) {
            int row_l = q * 8 + (tid >> 5);
            int col = (tid & 31) * 4;
            uint4 w = *(const uint4*)&Ep[row_l][col];
            size_t goff = (size_t)(m0 + p * 32 + row_l) * DE + n0 + col;
            half4 xe4 = *(const half4*)&Xe_h[goff];
            half4 r4;
            #pragma unroll
            for (int e = 0; e < 4; ++e) {
                half2v gt = __builtin_bit_cast(half2v, (&w.x)[e]);
                float g = (float)gt[0], t = (float)gt[1];
                float xe = (float)xe4[e];
                r4[e] = (_Float16)(g * xe + (1.f - g) * t);
            }
            *(half4*)&Xout[goff] = r4;
        }
    }
}

// ---- K2: conv1d(w=3,pad=1) — 128x128, 4 waves (R6 shape) + XCD swizzle ----
__global__ __launch_bounds__(256) void conv_pool_kernel(
    const _Float16* __restrict__ X, const _Float16* __restrict__ WcT,
    const float* __restrict__ bc, const int* __restrict__ mask,
    unsigned* __restrict__ pool)
{
    __shared__ __align__(16) _Float16 As[144][32];       // rows l0-8 .. l0+135
    __shared__ __align__(16) _Float16 Bs[3][128][32];
    __shared__ unsigned lpool[384];
    __shared__ int smask[128];
    __shared__ int anyNot[3];

    const int tid = threadIdx.x;
    const int lane = tid & 63, wid = tid >> 6;
    const int quad = lane >> 4, l15 = lane & 15;
    const int wm = (wid & 1) * 64, wn = (wid >> 1) * 64;
    const int linear = blockIdx.y * 6 + blockIdx.x;   // 0..1535
    const int xcd = linear & 7, kk = linear >> 3;     // kk 0..191
    const int n0 = (kk % 6) * 128;
    const int m0 = (xcd * 32 + kk / 6) * 128;
    const int b = m0 >> 9, l0 = m0 & 511;
    const int i4 = lane >> 2, c8 = (lane & 3) * 8;
    const int c8x = c8 ^ ((i4 & 3) * 8);
    const int rsw = (l15 & 3) * 8;

    if (tid < 3) anyNot[tid] = 0;
    for (int i = tid; i < 384; i += 256) lpool[i] = 0u;
    if (tid < 128) smask[tid] = mask[b * LL + l0 + tid];
    // pre-zero halo rows that OOB-masked lanes never write (persist across k)
    if (l0 == 0   && tid < 4) *(uint4*)&As[7][tid * 8]   = make_uint4(0u, 0u, 0u, 0u);
    if (l0 == 384 && tid < 4) *(uint4*)&As[136][tid * 8] = make_uint4(0u, 0u, 0u, 0u);
    __syncthreads();
    if (tid < 128) {
        int mv = smask[tid];
        if (mv != 1) atomicOr(&anyNot[0], 1);
        if (mv != 2) atomicOr(&anyNot[1], 1);
        if (mv != 3) atomicOr(&anyNot[2], 1);
    }

    floatx4 acc[4][4] = {};
    for (int k0 = 0; k0 < DE; k0 += 32) {
        __syncthreads();
        // A halo: 9 chunks of 16 rows; wave w: chunks w, w+4; wave 0 also 8
        #pragma unroll
        for (int t = 0; t < 2; ++t) {
            int c = wid + t * 4;
            int g = l0 - 8 + c * 16 + i4;
            if ((unsigned)g < (unsigned)LL)
                gload16(&X[((size_t)b * LL + g) * DE + k0 + c8x], &As[c * 16][0]);
        }
        if (wid == 0) {
            int g = l0 + 120 + i4;
            if ((unsigned)g < (unsigned)LL)
                gload16(&X[((size_t)b * LL + g) * DE + k0 + c8x], &As[128][0]);
        }
        // B: 3 shifts x 128 rows, 6 chunks per wave
        #pragma unroll
        for (int s = 0; s < 3; ++s) {
            #pragma unroll
            for (int t = 0; t < 2; ++t) {
                int rb = wid * 32 + t * 16;
                gload16(&WcT[(size_t)s * HD + (size_t)(n0 + rb + i4) * DE + k0 + c8x],
                        &Bs[s][rb][0]);
            }
        }
        __syncthreads();
        #pragma unroll
        for (int s = 0; s < 3; ++s) {
            half8 af[4], bf[4];
            #pragma unroll
            for (int i = 0; i < 4; ++i) {
                int pr = wm + i * 16 + l15 + s + 7;
                af[i] = *(half8*)&As[pr][(quad * 8) ^ ((pr & 3) * 8)];
            }
            #pragma unroll
            for (int j = 0; j < 4; ++j)
                bf[j] = *(half8*)&Bs[s][wn + j * 16 + l15][(quad * 8) ^ rsw];
            #pragma unroll
            for (int i = 0; i < 4; ++i)
                #pragma unroll
                for (int j = 0; j < 4; ++j)
                    acc[i][j] = __builtin_amdgcn_mfma_f32_16x16x32_f16(af[i], bf[j], acc[i][j], 0, 0, 0);
        }
    }

    // ---- fused masked max-pool epilogue ----
    float tmax[4][3];
    #pragma unroll
    for (int j = 0; j < 4; ++j)
        #pragma unroll
        for (int sg = 0; sg < 3; ++sg) tmax[j][sg] = -1e38f;

    #pragma unroll
    for (int i = 0; i < 4; ++i) {
        #pragma unroll
        for (int r = 0; r < 4; ++r) {
            int ll = wm + i * 16 + quad * 4 + r;
            int seg = smask[ll] - 1;
            if (seg >= 0) {
                #pragma unroll
                for (int j = 0; j < 4; ++j)
                    tmax[j][seg] = fmaxf(tmax[j][seg], acc[i][j][r]);
            }
        }
    }
    #pragma unroll
    for (int j = 0; j < 4; ++j) {
        int h = wn + j * 16 + l15;
        float bias = bc[n0 + h];
        #pragma unroll
        for (int sg = 0; sg < 3; ++sg)
            if (tmax[j][sg] > -1e37f)
                atomicMax(&lpool[h * 3 + sg], fkey(tmax[j][sg] + bias));
    }
    __syncthreads();
    for (int i = tid; i < 384; i += 256) {
        int hl = i / 3, k = i - hl * 3;
        unsigned key = lpool[i];
        if (anyNot[k]) {
            unsigned z = fkey(0.0f);
            if (z > key) key = z;
        }
        atomicMax(&pool[((size_t)b * HID + n0 + hl) * 3 + k], key);
    }
}

// ---- K3: out = tanh(untransform(pool)) ----
__global__ void finish_k(const unsigned* __restrict__ pool, float* __restrict__ out) {
    int idx = blockIdx.x * blockDim.x + threadIdx.x;
    if (idx < BB * HID * 3) out[idx] = tanhf(funkey(pool[idx]));
}

extern "C" void kernel_launch(void* const* d_in, const int* in_sizes, int n_in,
                              void* d_out, int out_size, void* d_ws, size_t ws_size,
                              hipStream_t stream) {
    const float* Xp = (const float*)d_in[0];
    const float* Xe = (const float*)d_in[1];
    const int*   Xm = (const int*)d_in[2];
    const float* W1 = (const float*)d_in[3];
    const float* b1 = (const float*)d_in[4];
    const float* W2 = (const float*)d_in[5];
    const float* b2 = (const float*)d_in[6];
    const float* Wc = (const float*)d_in[7];
    const float* bc = (const float*)d_in[8];
    float* out = (float*)d_out;

    // ws layout (101.5 MiB total)
    _Float16* Xe_h = (_Float16*)d_ws;                       // 48 MiB
    _Float16* X_h  = Xe_h + (size_t)M_TOT * DE;             // 48 MiB
    _Float16* W1_h = X_h + (size_t)M_TOT * DE;              // 1.125 MiB
    _Float16* W2_h = W1_h + (size_t)DE * DE;                // 0.47 MiB
    _Float16* WcT  = W2_h + (size_t)DE * DP;                // 3.375 MiB
    unsigned* pool = (unsigned*)(WcT + (size_t)3 * HD);     // 0.56 MiB

    hipMemsetAsync(pool, 0, (size_t)BB * HID * 3 * sizeof(unsigned), stream);
    prep_all<<<2048, 256, 0, stream>>>(Xe, W1, W2, Wc, Xe_h, W1_h, W2_h, WcT);
    gate_kernel<<<dim3(6, 256), 256, 0, stream>>>(
        Xe_h, Xp, W1_h, b1, W2_h, b2, X_h);
    conv_pool_kernel<<<dim3(6, 256), 256, 0, stream>>>(
        X_h, WcT, bc, Xm, pool);
    finish_k<<<(BB * HID * 3 + 255) / 256, 256, 0, stream>>>(pool, out);
}

// Round 10
// 434.533 us; speedup vs baseline: 1.0468x; 1.0468x over previous
//
#include <hip/hip_runtime.h>
#include <math.h>

#define DE 768
#define DP 320
#define HID 768
#define LL 512
#define BB 64
#define M_TOT (BB * LL)     // 32768 rows
#define HD (HID * DE)       // 589824

typedef _Float16 half8 __attribute__((ext_vector_type(8)));
typedef _Float16 half4 __attribute__((ext_vector_type(4)));
typedef _Float16 half2v __attribute__((ext_vector_type(2)));
typedef float floatx4 __attribute__((ext_vector_type(4)));

// async global->LDS, 16B per lane; LDS dest = wave-uniform base + lane*16
__device__ __forceinline__ void gload16(const void* g, void* l) {
    __builtin_amdgcn_global_load_lds(
        (const __attribute__((address_space(1))) unsigned int*)g,
        (__attribute__((address_space(3))) unsigned int*)l, 16, 0, 0);
}

// ---- fast transcendentals ----
__device__ __forceinline__ float fast_sigmoid(float x) {
    return __builtin_amdgcn_rcpf(1.f + __expf(-x));
}
__device__ __forceinline__ float fast_tanh(float x) {
    return 2.f * __builtin_amdgcn_rcpf(1.f + __expf(-2.f * x)) - 1.f;
}

// ---- monotone float <-> uint key (max via unsigned atomicMax) ----
__device__ __forceinline__ unsigned fkey(float v) {
    unsigned u = __float_as_uint(v);
    return (u & 0x80000000u) ? ~u : (u | 0x80000000u);
}
__device__ __forceinline__ float funkey(unsigned k) {
    unsigned u = (k & 0x80000000u) ? (k & 0x7FFFFFFFu) : ~k;
    return __uint_as_float(u);
}

// ---- prep: fp32->fp16 converts + Wc transpose, one-shot blocks ----
// [0,24576) Xe | [24576,25152) W1 | [25152,25392) W2 | [25392,27696) Wc |
// [27696,37936) Xp (only dispatched when ws allows Xp_h)
__global__ __launch_bounds__(256) void prep_all(
    const float* __restrict__ Xe, const float* __restrict__ W1,
    const float* __restrict__ W2, const float* __restrict__ Wc,
    const float* __restrict__ Xp,
    _Float16* __restrict__ Xe_h, _Float16* __restrict__ W1_h,
    _Float16* __restrict__ W2_h, _Float16* __restrict__ WcT,
    _Float16* __restrict__ Xp_h)
{
    const int bid = blockIdx.x, tid = threadIdx.x;
    if (bid < 24576) {
        int idx = bid * 256 + tid;
        float4 v = ((const float4*)Xe)[idx];
        half4 h = {(_Float16)v.x, (_Float16)v.y, (_Float16)v.z, (_Float16)v.w};
        *(half4*)&Xe_h[(size_t)idx * 4] = h;
    } else if (bid < 25152) {
        int idx = (bid - 24576) * 256 + tid;
        float4 v = ((const float4*)W1)[idx];
        half4 h = {(_Float16)v.x, (_Float16)v.y, (_Float16)v.z, (_Float16)v.w};
        *(half4*)&W1_h[(size_t)idx * 4] = h;
    } else if (bid < 25392) {
        int idx = (bid - 25152) * 256 + tid;
        float4 v = ((const float4*)W2)[idx];
        half4 h = {(_Float16)v.x, (_Float16)v.y, (_Float16)v.z, (_Float16)v.w};
        *(half4*)&W2_h[(size_t)idx * 4] = h;
    } else if (bid < 27696) {
        int idx = (bid - 25392) * 256 + tid;    // 0..589823 = h*DE+d
        float a = Wc[(size_t)idx * 3 + 0];
        float b = Wc[(size_t)idx * 3 + 1];
        float c = Wc[(size_t)idx * 3 + 2];
        WcT[idx]          = (_Float16)a;
        WcT[HD + idx]     = (_Float16)b;
        WcT[2 * HD + idx] = (_Float16)c;
    } else {
        int idx = (bid - 27696) * 256 + tid;    // Xp: 2,621,440 float4
        float4 v = ((const float4*)Xp)[idx];
        half4 h = {(_Float16)v.x, (_Float16)v.y, (_Float16)v.z, (_Float16)v.w};
        *(half4*)&Xp_h[(size_t)idx * 4] = h;
    }
}

// ---- K1: X = sigmoid(Xe*W1^T+b1)*Xe + (1-sig)*tanh(Xp*W2^T+b2) ----
// XPH=true: Xp pre-converted fp16 (phase A mirrors phase B).
template <bool XPH>
__global__ __launch_bounds__(256) void gate_kernel(
    const _Float16* __restrict__ Xe_h, const float* __restrict__ Xp,
    const _Float16* __restrict__ Xp_h,
    const _Float16* __restrict__ W1_h, const float* __restrict__ b1,
    const _Float16* __restrict__ W2_h, const float* __restrict__ b2,
    _Float16* __restrict__ Xout)
{
    __shared__ __align__(16) char smem[24576];
    _Float16 (*As)[32] = (_Float16 (*)[32])smem;            // A fp16, 8 KB
    float    (*Af)[32] = (float (*)[32])smem;               // A fp32 (fallback), 16 KB
    _Float16 (*Bs)[32] = (_Float16 (*)[32])(smem + 16384);  // B fp16, 8 KB
    unsigned (*Ep)[132] = (unsigned (*)[132])smem;          // epilogue (g,t)

    const int tid = threadIdx.x;
    const int lane = tid & 63, wid = tid >> 6;
    const int quad = lane >> 4, l15 = lane & 15;
    const int wm = (wid & 1) * 64, wn = (wid >> 1) * 64;
    const int linear = blockIdx.y * 6 + blockIdx.x;   // 0..1535
    const int xcd = linear & 7, kk = linear >> 3;     // kk 0..191
    const int n0 = (kk % 6) * 128;
    const int m0 = (xcd * 32 + kk / 6) * 128;
    const int i4 = lane >> 2, c8 = (lane & 3) * 8;
    const int c8x = c8 ^ ((i4 & 3) * 8);
    const int i8 = lane >> 3, c4 = (lane & 7) * 4;
    const int c4x = c4 ^ ((i8 & 3) * 8);
    const int rsw = (l15 & 3) * 8;

    floatx4 acc[4][4] = {};

    // ---- phase A: Xp (K=320) x W2_h^T ----
    for (int k0 = 0; k0 < DP; k0 += 32) {
        __syncthreads();
        if (XPH) {
            #pragma unroll
            for (int t = 0; t < 2; ++t) {
                int rb = wid * 32 + t * 16;
                gload16(&Xp_h[(size_t)(m0 + rb + i4) * DP + k0 + c8x], &As[rb][0]);
                gload16(&W2_h[(size_t)(n0 + rb + i4) * DP + k0 + c8x], &Bs[rb][0]);
            }
        } else {
            #pragma unroll
            for (int t = 0; t < 4; ++t) {
                int rb = wid * 32 + t * 8;
                gload16(&Xp[(size_t)(m0 + rb + i8) * DP + k0 + c4x], &Af[rb][0]);
            }
            #pragma unroll
            for (int t = 0; t < 2; ++t) {
                int rb = wid * 32 + t * 16;
                gload16(&W2_h[(size_t)(n0 + rb + i4) * DP + k0 + c8x], &Bs[rb][0]);
            }
        }
        __syncthreads();
        half8 af[4], bf[4];
        if (XPH) {
            #pragma unroll
            for (int i = 0; i < 4; ++i)
                af[i] = *(half8*)&As[wm + i * 16 + l15][(quad * 8) ^ rsw];
        } else {
            #pragma unroll
            for (int i = 0; i < 4; ++i) {
                int row = wm + i * 16 + l15;
                int sb = (quad * 8) ^ rsw;
                float4 x0 = *(float4*)&Af[row][sb];
                float4 x1 = *(float4*)&Af[row][sb + 4];
                half8 h = {(_Float16)x0.x, (_Float16)x0.y, (_Float16)x0.z, (_Float16)x0.w,
                           (_Float16)x1.x, (_Float16)x1.y, (_Float16)x1.z, (_Float16)x1.w};
                af[i] = h;
            }
        }
        #pragma unroll
        for (int j = 0; j < 4; ++j)
            bf[j] = *(half8*)&Bs[wn + j * 16 + l15][(quad * 8) ^ rsw];
        #pragma unroll
        for (int i = 0; i < 4; ++i)
            #pragma unroll
            for (int j = 0; j < 4; ++j)
                acc[i][j] = __builtin_amdgcn_mfma_f32_16x16x32_f16(af[i], bf[j], acc[i][j], 0, 0, 0);
    }

    // collapse acc -> t = tanh(acc + b2) packed fp16; reuse acc for phase B
    half4 tpk[4][4];
    #pragma unroll
    for (int j = 0; j < 4; ++j) {
        float b2v = b2[n0 + wn + j * 16 + l15];
        #pragma unroll
        for (int i = 0; i < 4; ++i) {
            half4 h;
            #pragma unroll
            for (int r = 0; r < 4; ++r)
                h[r] = (_Float16)fast_tanh(acc[i][j][r] + b2v);
            tpk[i][j] = h;
            acc[i][j] = (floatx4){0.f, 0.f, 0.f, 0.f};
        }
    }

    // ---- phase B: Xe_h fp16 (K=768) x W1_h^T ----
    for (int k0 = 0; k0 < DE; k0 += 32) {
        __syncthreads();
        #pragma unroll
        for (int t = 0; t < 2; ++t) {
            int rb = wid * 32 + t * 16;
            gload16(&Xe_h[(size_t)(m0 + rb + i4) * DE + k0 + c8x], &As[rb][0]);
            gload16(&W1_h[(size_t)(n0 + rb + i4) * DE + k0 + c8x], &Bs[rb][0]);
        }
        __syncthreads();
        half8 af[4], bf[4];
        #pragma unroll
        for (int i = 0; i < 4; ++i)
            af[i] = *(half8*)&As[wm + i * 16 + l15][(quad * 8) ^ rsw];
        #pragma unroll
        for (int j = 0; j < 4; ++j)
            bf[j] = *(half8*)&Bs[wn + j * 16 + l15][(quad * 8) ^ rsw];
        #pragma unroll
        for (int i = 0; i < 4; ++i)
            #pragma unroll
            for (int j = 0; j < 4; ++j)
                acc[i][j] = __builtin_amdgcn_mfma_f32_16x16x32_f16(af[i], bf[j], acc[i][j], 0, 0, 0);
    }

    // ---- epilogue via LDS: coalesced global IO ----
    float b1v[4];
    #pragma unroll
    for (int j = 0; j < 4; ++j) b1v[j] = b1[n0 + wn + j * 16 + l15];

    #pragma unroll
    for (int p = 0; p < 4; ++p) {
        __syncthreads();
        if ((wm >> 6) == (p >> 1)) {
            #pragma unroll
            for (int ii = 0; ii < 2; ++ii) {
                int i = (p & 1) * 2 + ii;
                #pragma unroll
                for (int j = 0; j < 4; ++j) {
                    int col = wn + j * 16 + l15;
                    #pragma unroll
                    for (int r = 0; r < 4; ++r) {
                        int row_l = ii * 16 + quad * 4 + r;
                        float g = fast_sigmoid(acc[i][j][r] + b1v[j]);
                        half2v gt;
                        gt[0] = (_Float16)g;
                        gt[1] = tpk[i][j][r];
                        Ep[row_l][col] = __builtin_bit_cast(unsigned, gt);
                    }
                }
            }
        }
        __syncthreads();
        #pragma unroll
        for (int q = 0; q < 4; ++q) {
            int row_l = q * 8 + (tid >> 5);
            int col = (tid & 31) * 4;
            uint4 w = *(const uint4*)&Ep[row_l][col];
            size_t goff = (size_t)(m0 + p * 32 + row_l) * DE + n0 + col;
            half4 xe4 = *(const half4*)&Xe_h[goff];
            half4 r4;
            #pragma unroll
            for (int e = 0; e < 4; ++e) {
                half2v gt = __builtin_bit_cast(half2v, (&w.x)[e]);
                float g = (float)gt[0], t = (float)gt[1];
                float xe = (float)xe4[e];
                r4[e] = (_Float16)(g * xe + (1.f - g) * t);
            }
            *(half4*)&Xout[goff] = r4;
        }
    }
}

// ---- K2: conv1d(w=3,pad=1) — 128x128, 4 waves, halo A, XCD swizzle ----
__global__ __launch_bounds__(256) void conv_pool_kernel(
    const _Float16* __restrict__ X, const _Float16* __restrict__ WcT,
    const float* __restrict__ bc, const int* __restrict__ mask,
    unsigned* __restrict__ pool)
{
    __shared__ __align__(16) _Float16 As[144][32];       // rows l0-8 .. l0+135
    __shared__ __align__(16) _Float16 Bs[3][128][32];
    __shared__ unsigned lpool[384];
    __shared__ int smask[128];
    __shared__ int anyNot[3];

    const int tid = threadIdx.x;
    const int lane = tid & 63, wid = tid >> 6;
    const int quad = lane >> 4, l15 = lane & 15;
    const int wm = (wid & 1) * 64, wn = (wid >> 1) * 64;
    const int linear = blockIdx.y * 6 + blockIdx.x;   // 0..1535
    const int xcd = linear & 7, kk = linear >> 3;     // kk 0..191
    const int n0 = (kk % 6) * 128;
    const int m0 = (xcd * 32 + kk / 6) * 128;
    const int b = m0 >> 9, l0 = m0 & 511;
    const int i4 = lane >> 2, c8 = (lane & 3) * 8;
    const int c8x = c8 ^ ((i4 & 3) * 8);
    const int rsw = (l15 & 3) * 8;

    if (tid < 3) anyNot[tid] = 0;
    for (int i = tid; i < 384; i += 256) lpool[i] = 0u;
    if (tid < 128) smask[tid] = mask[b * LL + l0 + tid];
    if (l0 == 0   && tid < 4) *(uint4*)&As[7][tid * 8]   = make_uint4(0u, 0u, 0u, 0u);
    if (l0 == 384 && tid < 4) *(uint4*)&As[136][tid * 8] = make_uint4(0u, 0u, 0u, 0u);
    __syncthreads();
    if (tid < 128) {
        int mv = smask[tid];
        if (mv != 1) atomicOr(&anyNot[0], 1);
        if (mv != 2) atomicOr(&anyNot[1], 1);
        if (mv != 3) atomicOr(&anyNot[2], 1);
    }

    floatx4 acc[4][4] = {};
    for (int k0 = 0; k0 < DE; k0 += 32) {
        __syncthreads();
        #pragma unroll
        for (int t = 0; t < 2; ++t) {
            int c = wid + t * 4;
            int g = l0 - 8 + c * 16 + i4;
            if ((unsigned)g < (unsigned)LL)
                gload16(&X[((size_t)b * LL + g) * DE + k0 + c8x], &As[c * 16][0]);
        }
        if (wid == 0) {
            int g = l0 + 120 + i4;
            if ((unsigned)g < (unsigned)LL)
                gload16(&X[((size_t)b * LL + g) * DE + k0 + c8x], &As[128][0]);
        }
        #pragma unroll
        for (int s = 0; s < 3; ++s) {
            #pragma unroll
            for (int t = 0; t < 2; ++t) {
                int rb = wid * 32 + t * 16;
                gload16(&WcT[(size_t)s * HD + (size_t)(n0 + rb + i4) * DE + k0 + c8x],
                        &Bs[s][rb][0]);
            }
        }
        __syncthreads();
        #pragma unroll
        for (int s = 0; s < 3; ++s) {
            half8 af[4], bf[4];
            #pragma unroll
            for (int i = 0; i < 4; ++i) {
                int pr = wm + i * 16 + l15 + s + 7;
                af[i] = *(half8*)&As[pr][(quad * 8) ^ ((pr & 3) * 8)];
            }
            #pragma unroll
            for (int j = 0; j < 4; ++j)
                bf[j] = *(half8*)&Bs[s][wn + j * 16 + l15][(quad * 8) ^ rsw];
            #pragma unroll
            for (int i = 0; i < 4; ++i)
                #pragma unroll
                for (int j = 0; j < 4; ++j)
                    acc[i][j] = __builtin_amdgcn_mfma_f32_16x16x32_f16(af[i], bf[j], acc[i][j], 0, 0, 0);
        }
    }

    // ---- fused masked max-pool epilogue ----
    float tmax[4][3];
    #pragma unroll
    for (int j = 0; j < 4; ++j)
        #pragma unroll
        for (int sg = 0; sg < 3; ++sg) tmax[j][sg] = -1e38f;

    #pragma unroll
    for (int i = 0; i < 4; ++i) {
        #pragma unroll
        for (int r = 0; r < 4; ++r) {
            int ll = wm + i * 16 + quad * 4 + r;
            int seg = smask[ll] - 1;
            if (seg >= 0) {
                #pragma unroll
                for (int j = 0; j < 4; ++j)
                    tmax[j][seg] = fmaxf(tmax[j][seg], acc[i][j][r]);
            }
        }
    }
    #pragma unroll
    for (int j = 0; j < 4; ++j) {
        int h = wn + j * 16 + l15;
        float bias = bc[n0 + h];
        #pragma unroll
        for (int sg = 0; sg < 3; ++sg)
            if (tmax[j][sg] > -1e37f)
                atomicMax(&lpool[h * 3 + sg], fkey(tmax[j][sg] + bias));
    }
    __syncthreads();
    for (int i = tid; i < 384; i += 256) {
        int hl = i / 3, k = i - hl * 3;
        unsigned key = lpool[i];
        if (anyNot[k]) {
            unsigned z = fkey(0.0f);
            if (z > key) key = z;
        }
        atomicMax(&pool[((size_t)b * HID + n0 + hl) * 3 + k], key);
    }
}

// ---- K3: out = tanh(untransform(pool)) ----
__global__ void finish_k(const unsigned* __restrict__ pool, float* __restrict__ out) {
    int idx = blockIdx.x * blockDim.x + threadIdx.x;
    if (idx < BB * HID * 3) out[idx] = tanhf(funkey(pool[idx]));
}

extern "C" void kernel_launch(void* const* d_in, const int* in_sizes, int n_in,
                              void* d_out, int out_size, void* d_ws, size_t ws_size,
                              hipStream_t stream) {
    const float* Xp = (const float*)d_in[0];
    const float* Xe = (const float*)d_in[1];
    const int*   Xm = (const int*)d_in[2];
    const float* W1 = (const float*)d_in[3];
    const float* b1 = (const float*)d_in[4];
    const float* W2 = (const float*)d_in[5];
    const float* b2 = (const float*)d_in[6];
    const float* Wc = (const float*)d_in[7];
    const float* bc = (const float*)d_in[8];
    float* out = (float*)d_out;

    // ws layout: base 101.5 MiB (+20 MiB Xp_h if it fits)
    _Float16* Xe_h = (_Float16*)d_ws;                       // 48 MiB
    _Float16* X_h  = Xe_h + (size_t)M_TOT * DE;             // 48 MiB
    _Float16* W1_h = X_h + (size_t)M_TOT * DE;              // 1.125 MiB
    _Float16* W2_h = W1_h + (size_t)DE * DE;                // 0.47 MiB
    _Float16* WcT  = W2_h + (size_t)DE * DP;                // 3.375 MiB
    unsigned* pool = (unsigned*)(WcT + (size_t)3 * HD);     // 0.56 MiB
    _Float16* Xp_h = (_Float16*)(pool + (size_t)BB * HID * 3);  // 20 MiB tail

    const size_t need_xph =
        ((char*)(Xp_h + (size_t)M_TOT * DP)) - (char*)d_ws;
    const bool use_xph = ws_size >= need_xph;

    hipMemsetAsync(pool, 0, (size_t)BB * HID * 3 * sizeof(unsigned), stream);
    prep_all<<<use_xph ? 37936 : 27696, 256, 0, stream>>>(
        Xe, W1, W2, Wc, Xp, Xe_h, W1_h, W2_h, WcT, Xp_h);
    if (use_xph)
        gate_kernel<true><<<dim3(6, 256), 256, 0, stream>>>(
            Xe_h, Xp, Xp_h, W1_h, b1, W2_h, b2, X_h);
    else
        gate_kernel<false><<<dim3(6, 256), 256, 0, stream>>>(
            Xe_h, Xp, Xp_h, W1_h, b1, W2_h, b2, X_h);
    conv_pool_kernel<<<dim3(6, 256), 256, 0, stream>>>(
        X_h, WcT, bc, Xm, pool);
    finish_k<<<(BB * HID * 3 + 255) / 256, 256, 0, stream>>>(pool, out);
}